// Round 8
// baseline (283.556 us; speedup 1.0000x reference)
//
#include <hip/hip_runtime.h>
#include <hip/hip_bf16.h>

#define T_TOK 2048
#define HDIM 1024
#define IDIM 512
#define ISDIM 1024
#define NEXP 16
#define TOPK 4
#define NSLOT (T_TOK*TOPK)
#define SCALE_F 2.5f

typedef unsigned short u16;
typedef float f32x4 __attribute__((ext_vector_type(4)));
typedef __bf16 bf16x8 __attribute__((ext_vector_type(8)));
typedef u16 u16x8 __attribute__((ext_vector_type(8)));

__device__ __forceinline__ u16 f2bf(float f) {
  unsigned u = __builtin_bit_cast(unsigned, f);
  u += 0x7fffu + ((u >> 16) & 1u);   // round-to-nearest-even
  return (u16)(u >> 16);
}

__device__ __forceinline__ float bf2f(u16 h) {
  unsigned u = ((unsigned)h) << 16;
  return __builtin_bit_cast(float, u);
}

__device__ __forceinline__ void gload_lds16(const u16* g, u16* l) {
  // async global->LDS, 16B/lane; data lands at (wave-uniform l) + lane*16
  __builtin_amdgcn_global_load_lds(
      (const __attribute__((address_space(1))) void*)g,
      (__attribute__((address_space(3))) void*)l, 16, 0, 0);
}

__device__ __forceinline__ f32x4 mfma16(u16x8 a, u16x8 b, f32x4 c) {
  return __builtin_amdgcn_mfma_f32_16x16x32_bf16(
      __builtin_bit_cast(bf16x8, a), __builtin_bit_cast(bf16x8, b), c, 0, 0, 0);
}

// quad (float4) counts for weight conversion
#define N1Q (NEXP*IDIM*HDIM/4)     // 2097152 -> 8192 blocks
#define NS1Q (ISDIM*HDIM/4)        // 262144  -> 1024 blocks
#define CVT_BLK ((N1Q + NS1Q) / 256)   // 9216

__device__ __forceinline__ void cvt_quad(const float* src, u16* dst, int off) {
  float4 v = reinterpret_cast<const float4*>(src)[off];
  ushort4 o;
  o.x = f2bf(v.x); o.y = f2bf(v.y); o.z = f2bf(v.z); o.w = f2bf(v.w);
  reinterpret_cast<ushort4*>(dst)[off] = o;
}

// ---------------- router + W1/Ws1 conversion (fused, one launch) ----------
// blocks < T_TOK: routing for token t.  blocks >= T_TOK: fp32->bf16 convert
// of W1/Ws1 (their traffic rides the router's idle memory pipe; kernel
// boundary orders them before phase A which consumes W1b/Ws1b).
__global__ void __launch_bounds__(256) router_kernel(
    const float* __restrict__ x, const float* __restrict__ Wg,
    const float* __restrict__ bias,
    int* __restrict__ topk_idx, float* __restrict__ topk_w,
    u16* __restrict__ Xbf,
    const float* __restrict__ W1, const float* __restrict__ Ws1,
    u16* __restrict__ W1b, u16* __restrict__ Ws1b) {
  int t = blockIdx.x;
  int tid = threadIdx.x;
  if (t >= T_TOK) {
    int i = (t - T_TOK) * 256 + tid;
    if (i < N1Q) cvt_quad(W1, W1b, i);
    else         cvt_quad(Ws1, Ws1b, i - N1Q);
    return;
  }
  int lane = tid & 63;
  int wave = tid >> 6;

  __shared__ __align__(16) float sx[HDIM];
  __shared__ float ssc[NEXP];

  float4 xv = reinterpret_cast<const float4*>(x + (size_t)t * HDIM)[tid];
  reinterpret_cast<float4*>(sx)[tid] = xv;
  ushort4 o;
  o.x = f2bf(xv.x); o.y = f2bf(xv.y); o.z = f2bf(xv.z); o.w = f2bf(xv.w);
  reinterpret_cast<ushort4*>(Xbf + (size_t)t * HDIM)[tid] = o;
  __syncthreads();

  float acc[4] = {0.f, 0.f, 0.f, 0.f};
  const float4* sx4 = reinterpret_cast<const float4*>(sx);
#pragma unroll
  for (int c = 0; c < 4; c++) {
    float4 xq = sx4[lane + 64 * c];
#pragma unroll
    for (int e = 0; e < 4; e++) {
      float4 wq = reinterpret_cast<const float4*>(
          Wg + (size_t)(wave * 4 + e) * HDIM)[lane + 64 * c];
      acc[e] += xq.x * wq.x + xq.y * wq.y + xq.z * wq.z + xq.w * wq.w;
    }
  }
#pragma unroll
  for (int e = 0; e < 4; e++) {
    float v = acc[e];
#pragma unroll
    for (int off = 32; off > 0; off >>= 1) v += __shfl_xor(v, off);
    if (lane == 0) ssc[wave * 4 + e] = v;
  }
  __syncthreads();

  if (tid == 0) {
    float scores[NEXP], sc[NEXP];
#pragma unroll
    for (int e = 0; e < NEXP; e++) {
      float s = 1.f / (1.f + expf(-ssc[e]));
      scores[e] = s;
      sc[e] = s + bias[e];
    }
    float gsum[4];
#pragma unroll
    for (int g = 0; g < 4; g++) {
      float a = sc[4*g], b = sc[4*g+1], c = sc[4*g+2], d = sc[4*g+3];
      float hi1 = fmaxf(a, b), lo1 = fminf(a, b);
      float hi2 = fmaxf(c, d), lo2 = fminf(c, d);
      gsum[g] = fmaxf(hi1, hi2) + fmaxf(fminf(hi1, hi2), fmaxf(lo1, lo2));
    }
    int g0 = 0; float bv = gsum[0];
#pragma unroll
    for (int g = 1; g < 4; g++) if (gsum[g] > bv) { bv = gsum[g]; g0 = g; }
    int g1 = -1; float bv2 = -1e30f;
#pragma unroll
    for (int g = 0; g < 4; g++) if (g != g0 && gsum[g] > bv2) { bv2 = gsum[g]; g1 = g; }
    float m[NEXP];
#pragma unroll
    for (int e = 0; e < NEXP; e++) {
      int g = e >> 2;
      m[e] = (g == g0 || g == g1) ? sc[e] : 0.0f;
    }
    int idx[TOPK]; float w[TOPK];
#pragma unroll
    for (int k = 0; k < TOPK; k++) {
      int bj = 0; float bmv = m[0];
#pragma unroll
      for (int j = 1; j < NEXP; j++) if (m[j] > bmv) { bmv = m[j]; bj = j; }
      idx[k] = bj; w[k] = scores[bj];
#pragma unroll
      for (int j = 0; j < NEXP; j++) m[j] = (j == bj) ? -1e30f : m[j];
    }
    float s4 = w[0] + w[1] + w[2] + w[3] + 1e-20f;
    float inv = SCALE_F / s4;
#pragma unroll
    for (int k = 0; k < TOPK; k++) {
      topk_idx[t * TOPK + k] = idx[k];
      topk_w[t * TOPK + k] = w[k] * inv;
    }
  }
}

// ---------------- route_build: histogram + scan + scatter + inverse map ----
__global__ void __launch_bounds__(256) route_build(
    const int* __restrict__ topk_idx, const float* __restrict__ topk_w,
    int* __restrict__ offsets, int* __restrict__ counts,
    int* __restrict__ perm_token, float* __restrict__ perm_w,
    int* __restrict__ slot_of) {
  __shared__ int hcnt[NEXP];
  __shared__ int hfill[NEXP];
  int tid = threadIdx.x;
  if (tid < NEXP) hcnt[tid] = 0;
  __syncthreads();

  int e_loc[NSLOT / 256];
#pragma unroll
  for (int i = 0; i < NSLOT / 256; i++) {
    int j = tid + 256 * i;
    int e = topk_idx[j];
    e_loc[i] = e;
    atomicAdd(&hcnt[e], 1);
  }
  __syncthreads();

  if (tid == 0) {
    int s = 0;
#pragma unroll
    for (int e = 0; e < NEXP; e++) {
      int c = hcnt[e];
      offsets[e] = s;
      counts[e] = c;
      hfill[e] = s;
      s += c;
    }
  }
  __syncthreads();

#pragma unroll
  for (int i = 0; i < NSLOT / 256; i++) {
    int j = tid + 256 * i;
    int pos = atomicAdd(&hfill[e_loc[i]], 1);
    perm_token[pos] = j >> 2;
    perm_w[pos] = topk_w[j];
    slot_of[j] = pos;
  }
}

// ---------------- fused MoE GEMM v5: dbuf LDS + XCD remap + fused cvt -----
// R7: FETCH fixed (23MB) but MfmaUtil still 8% -- serial K-loop latency at
// ~1 effective block/CU (every iter: DMA -> vmcnt(0)+barrier -> compute).
// v5: double-buffered LDS (48KB, 3 blocks/CU): prefetch tile k+1 into the
// other buffer BEFORE computing tile k; ONE barrier/iter. Phase A also
// carries the W2/Ws2 fp32->bf16 conversion on extra blocks (rides the
// latency-stalled memory pipe; phase boundary orders it before phase B).
// PHASE 0 (KL=1024): e<16: Hg[slot]=w*relu2(x[tok] @ W1[e]^T)   (bf16)
//                    e=16: Hs = relu2(x @ Ws1^T)                (bf16)
// PHASE 1 (KL=512):  e<16: Ygb[slot] = Hg[slot] @ W2[e]^T       (bf16)
//                    e=16/17: Ys[half] = Hs[:,half] @ Ws2[:,half]^T (fp32)
#define BM 64
#define BN 128
#define BK 64
#define NT_A ((T_TOK/BM)*(ISDIM/BN)*(NEXP+1))   // 4352 GEMM items, phase A
#define GRID_A (NT_A + CVT_BLK)                  // 13568 (div by 8)
#define NT_B ((T_TOK/BM)*(HDIM/BN)*(NEXP+2))    // 4608, phase B

template<int PHASE>
__global__ void __launch_bounds__(256) moe_gemm(
    const u16* __restrict__ Xbf, const u16* __restrict__ Hg,
    const u16* __restrict__ Hs,
    const u16* __restrict__ W1b, const u16* __restrict__ W2b,
    const u16* __restrict__ Ws1b, const u16* __restrict__ Ws2b,
    const int* __restrict__ eoffs, const int* __restrict__ ecnts,
    const int* __restrict__ rowmap, const float* __restrict__ rowscale,
    u16* __restrict__ HgOut, u16* __restrict__ HsOut,
    u16* __restrict__ Ygb, float* __restrict__ Ys,
    const float* __restrict__ W2f, const float* __restrict__ Ws2f,
    u16* __restrict__ W2bo, u16* __restrict__ Ws2bo)
{
  constexpr int KL = (PHASE == 0) ? HDIM : IDIM;   // uniform loop extent
  int tid = threadIdx.x;

  // XCD-locality remap over 1-D grid (consecutive flat ids -> XCDs rr)
  int flat = blockIdx.x;
  int chunk = gridDim.x >> 3;
  int widx = (flat & 7) * chunk + (flat >> 3);

  if (PHASE == 0 && widx >= NT_A) {
    int i = (widx - NT_A) * 256 + tid;           // fused W2/Ws2 conversion
    if (i < N1Q) cvt_quad(W2f, W2bo, i);
    else         cvt_quad(Ws2f, Ws2bo, i - N1Q);
    return;
  }

  int mb = widx % (T_TOK / BM);
  int tmp = widx / (T_TOK / BM);
  int nb = tmp % (((PHASE == 0) ? ISDIM : HDIM) / BN);
  int e  = tmp / (((PHASE == 0) ? ISDIM : HDIM) / BN);

  bool sh = (e >= NEXP);
  int half = e - NEXP;                              // phase-1 shared K-half
  int N, Mloc, rowbase, Astr, Bstr, kb;
  const u16* Abase;
  const u16* Bp;
  if (PHASE == 0) {
    Astr = HDIM; Bstr = HDIM; kb = 0;
    if (sh) { N = ISDIM; Mloc = T_TOK; rowbase = 0; Abase = Xbf; Bp = Ws1b; }
    else    { N = IDIM; Mloc = ecnts[e]; rowbase = eoffs[e]; Abase = Xbf;
              Bp = W1b + (size_t)e * IDIM * HDIM; }
  } else {
    N = HDIM;
    if (sh) { Astr = ISDIM; Bstr = ISDIM; kb = half * IDIM;
              Mloc = T_TOK; rowbase = 0; Abase = Hs; Bp = Ws2b; }
    else    { Astr = IDIM; Bstr = IDIM; kb = 0;
              Mloc = ecnts[e]; rowbase = eoffs[e]; Abase = Hg;
              Bp = W2b + (size_t)e * HDIM * IDIM; }
  }
  int m0 = mb * BM;
  if (m0 >= Mloc) return;
  int n0 = nb * BN;
  if (n0 >= N) return;

  // double-buffered, unpadded (global_load_lds base+lane*16 placement)
  __shared__ __align__(16) u16 sA[2 * BM * BK];   // 2 x 8 KB
  __shared__ __align__(16) u16 sB[2 * BN * BK];   // 2 x 16 KB

  int lane = tid & 63;
  int wave = tid >> 6;
  int wm = (wave >> 1) * 32;   // wave computes 32x64 of the 64x128 tile
  int wn = (wave & 1) * 64;
  int fm = lane & 15;
  int kq = lane >> 4;          // 0..3
  int fsw = fm & 7;            // row&7 for fragment-row fm

  // staging: lane -> row (lane>>3), LDS chunk (lane&7); source chunk is
  // XOR-swizzled so LDS chunk l of row r holds global chunk l ^ (r&7)
  int lrow8 = lane >> 3;       // 0..7
  int sch = ((lane & 7) ^ lrow8) * 8;   // swizzled source k-offset (elems)

  const u16* AgP[2];
  u16* sAw[2];
#pragma unroll
  for (int g = 0; g < 2; g++) {
    int rt = 16 * wave + 8 * g + lrow8;
    int ar = m0 + rt;
    int arc = (ar < Mloc) ? ar : (Mloc - 1);        // clamp; stores masked
    size_t asrc;
    if (PHASE == 0 && !sh) asrc = (size_t)rowmap[rowbase + arc] * Astr;
    else                   asrc = (size_t)((sh ? 0 : rowbase) + arc) * Astr;
    AgP[g] = Abase + asrc + kb + sch;
    sAw[g] = &sA[(16 * wave + 8 * g) * BK];
  }
  const u16* BgP[4];
  u16* sBw[4];
#pragma unroll
  for (int g = 0; g < 4; g++) {
    int rt = 32 * wave + 8 * g + lrow8;
    BgP[g] = Bp + (size_t)(n0 + rt) * Bstr + kb + sch;
    sBw[g] = &sB[(32 * wave + 8 * g) * BK];
  }

  auto stage = [&](int buf, int k0) {
#pragma unroll
    for (int g = 0; g < 2; g++) gload_lds16(AgP[g] + k0, sAw[g] + buf * (BM * BK));
#pragma unroll
    for (int g = 0; g < 4; g++) gload_lds16(BgP[g] + k0, sBw[g] + buf * (BN * BK));
  };

  f32x4 acc[2][4] = {};

  stage(0, 0);
  __syncthreads();              // drain prologue DMA
  int cur = 0;
  for (int k0 = 0; k0 < KL; k0 += BK) {
    if (k0 + BK < KL) stage(cur ^ 1, k0 + BK);   // prefetch overlaps compute
#pragma unroll
    for (int ks = 0; ks < 2; ks++) {
      int ch = ((ks * 4 + kq) ^ fsw) * 8;   // un-swizzle at read
      u16x8 af[2], bf[4];
#pragma unroll
      for (int i = 0; i < 2; i++)
        af[i] = *reinterpret_cast<const u16x8*>(
            &sA[cur * (BM * BK) + (wm + 16 * i + fm) * BK + ch]);
#pragma unroll
      for (int j = 0; j < 4; j++)
        bf[j] = *reinterpret_cast<const u16x8*>(
            &sB[cur * (BN * BK) + (wn + 16 * j + fm) * BK + ch]);
#pragma unroll
      for (int i = 0; i < 2; i++)
#pragma unroll
        for (int j = 0; j < 4; j++)
          acc[i][j] = mfma16(af[i], bf[j], acc[i][j]);
    }
    __syncthreads();            // one barrier/iter: drains prefetch + reads
    cur ^= 1;
  }

  // epilogue: C/D mapping col = lane&15, row = (lane>>4)*4 + reg (m89/m91)
#pragma unroll
  for (int i = 0; i < 2; i++) {
#pragma unroll
    for (int j = 0; j < 4; j++) {
      int gn = n0 + wn + 16 * j + fm;
      f32x4 a = acc[i][j];
#pragma unroll
      for (int r = 0; r < 4; r++) {
        int gm = m0 + wm + 16 * i + kq * 4 + r;
        if (gm < Mloc) {
          float v = a[r];
          if (PHASE == 0) {
            float tq = fmaxf(v, 0.f);
            if (!sh) {
              tq = tq * tq * rowscale[rowbase + gm];
              HgOut[(size_t)(rowbase + gm) * IDIM + gn] = f2bf(tq);
            } else {
              HsOut[(size_t)gm * ISDIM + gn] = f2bf(tq * tq);
            }
          } else {
            if (!sh) Ygb[(size_t)(rowbase + gm) * HDIM + gn] = f2bf(v);
            else     Ys[(size_t)(half * T_TOK + gm) * HDIM + gn] = v;
          }
        }
      }
    }
  }
}

// ---- combine: out[t] = Ys0[t] + Ys1[t] + sum_k Ygb[slot_of[t,k]] ---------
__global__ void __launch_bounds__(256) combine_kernel(
    const u16* __restrict__ Ygb, const float* __restrict__ Ys,
    const int* __restrict__ slot_of, float* __restrict__ out) {
  int t = blockIdx.x;
  int i = threadIdx.x;                       // 256 x 4 elems = 1024
  int4 s = *reinterpret_cast<const int4*>(&slot_of[t * 4]);
  const ushort4* Y4 = reinterpret_cast<const ushort4*>(Ygb);
  const float4* S4 = reinterpret_cast<const float4*>(Ys);
  float4* O4 = reinterpret_cast<float4*>(out);
  float4 v0 = S4[(size_t)t * 256 + i];
  float4 v1 = S4[(size_t)(T_TOK + t) * 256 + i];
  ushort4 a = Y4[(size_t)s.x * 256 + i];
  ushort4 b = Y4[(size_t)s.y * 256 + i];
  ushort4 c = Y4[(size_t)s.z * 256 + i];
  ushort4 d = Y4[(size_t)s.w * 256 + i];
  float4 v;
  v.x = v0.x + v1.x + bf2f(a.x) + bf2f(b.x) + bf2f(c.x) + bf2f(d.x);
  v.y = v0.y + v1.y + bf2f(a.y) + bf2f(b.y) + bf2f(c.y) + bf2f(d.y);
  v.z = v0.z + v1.z + bf2f(a.z) + bf2f(b.z) + bf2f(c.z) + bf2f(d.z);
  v.w = v0.w + v1.w + bf2f(a.w) + bf2f(b.w) + bf2f(c.w) + bf2f(d.w);
  O4[(size_t)t * 256 + i] = v;
}

// ---------------- launcher ----------------
extern "C" void kernel_launch(void* const* d_in, const int* in_sizes, int n_in,
                              void* d_out, int out_size, void* d_ws, size_t ws_size,
                              hipStream_t stream) {
  const float* x    = (const float*)d_in[0];
  const float* Wg   = (const float*)d_in[1];
  const float* bias = (const float*)d_in[2];
  const float* W1   = (const float*)d_in[3];
  const float* W2   = (const float*)d_in[4];
  const float* Ws1  = (const float*)d_in[5];
  const float* Ws2  = (const float*)d_in[6];
  float* out = (float*)d_out;

  char* p = (char*)d_ws;
  auto alloc = [&](size_t bytes) -> void* {
    void* r = (void*)p;
    p += (bytes + 255) & ~(size_t)255;
    return r;
  };
  int*   topk_idx   = (int*)  alloc((size_t)NSLOT * 4);
  float* topk_w     = (float*)alloc((size_t)NSLOT * 4);
  int*   counts     = (int*)  alloc(64);
  int*   offsets    = (int*)  alloc(64);
  int*   perm_token = (int*)  alloc((size_t)NSLOT * 4);
  float* perm_w     = (float*)alloc((size_t)NSLOT * 4);
  int*   slot_of    = (int*)  alloc((size_t)NSLOT * 4);
  u16*   Xbf        = (u16*)  alloc((size_t)T_TOK * HDIM * 2);
  u16*   W1b        = (u16*)  alloc((size_t)NEXP * IDIM * HDIM * 2);
  u16*   W2b        = (u16*)  alloc((size_t)NEXP * HDIM * IDIM * 2);
  u16*   Ws1b      = (u16*)  alloc((size_t)ISDIM * HDIM * 2);
  u16*   Ws2b      = (u16*)  alloc((size_t)HDIM * ISDIM * 2);
  u16*   Hg         = (u16*)  alloc((size_t)NSLOT * IDIM * 2);
  u16*   Hs         = (u16*)  alloc((size_t)T_TOK * ISDIM * 2);
  u16*   Ygb        = (u16*)  alloc((size_t)NSLOT * HDIM * 2);
  float* Ys         = (float*)alloc((size_t)2 * T_TOK * HDIM * 4);

  // router + W1/Ws1 cvt (one launch)
  router_kernel<<<T_TOK + CVT_BLK, 256, 0, stream>>>(
      x, Wg, bias, topk_idx, topk_w, Xbf, W1, Ws1, W1b, Ws1b);
  route_build<<<1, 256, 0, stream>>>(topk_idx, topk_w, offsets, counts,
                                     perm_token, perm_w, slot_of);

  // phase A: routed up (e<16) + shared up (e=16) + W2/Ws2 cvt, one launch
  moe_gemm<0><<<GRID_A, 256, 0, stream>>>(
      Xbf, Hg, Hs, W1b, W2b, Ws1b, Ws2b, offsets, counts,
      perm_token, perm_w, Hg, Hs, nullptr, nullptr,
      W2, Ws2, W2b, Ws2b);

  // phase B: routed down (e<16) + shared down split-K (e=16,17), one launch
  moe_gemm<1><<<NT_B, 256, 0, stream>>>(
      Xbf, Hg, Hs, W1b, W2b, Ws1b, Ws2b, offsets, counts,
      perm_token, perm_w, Hg, Hs, Ygb, Ys,
      nullptr, nullptr, nullptr, nullptr);

  // combine: out[t] = Ys0 + Ys1 + sum_k Ygb[slot_of[t,k]]
  combine_kernel<<<T_TOK, 256, 0, stream>>>(Ygb, Ys, slot_of, out);
}